// Round 16
// baseline (374.151 us; speedup 1.0000x reference)
//
#include <hip/hip_runtime.h>

#define T_   2048
#define BB   2
#define CC   2048
#define HH   16
#define GG   4
#define HSS  128
#define QKVD 3072          // (H+2G)*HS
#define NQKV 3088          // + H gate cols
#define NPAD 3200          // padded to 25*128
#define SCALE_ 0.08838834764831845f   // 1/sqrt(128)
#define SCALE2_ (0.08838834764831845f * 1.4426950408889634f)   // 1/sqrt(128) * log2(e)

typedef __attribute__((ext_vector_type(8))) short  short8;
typedef __attribute__((ext_vector_type(4))) float  f32x4;
typedef __attribute__((ext_vector_type(4))) int    v4i;
typedef __attribute__((ext_vector_type(4))) float  v4f;
typedef __attribute__((ext_vector_type(4))) unsigned short u16x4;

typedef const void __attribute__((address_space(1)))* gas1_t;
typedef void __attribute__((address_space(3)))* as3_t;

__device__ __forceinline__ void gl_lds16(const void* g, void* l) {
    __builtin_amdgcn_global_load_lds((gas1_t)g, (as3_t)l, 16, 0, 0);
}

__device__ __forceinline__ unsigned short f2bf(float f) {
    unsigned u = __float_as_uint(f);
    u += 0x7fffu + ((u >> 16) & 1u);   // RNE
    return (unsigned short)(u >> 16);
}
// round-half-up: P values are positive exp2 outputs, bias negligible, 2 ops not 4
__device__ __forceinline__ unsigned short f2bf_fast(float f) {
    return (unsigned short)((__float_as_uint(f) + 0x8000u) >> 16);
}
__device__ __forceinline__ float bf2f(unsigned short h) {
    return __uint_as_float(((unsigned)h) << 16);
}

// DPP cross-lane move within a 16-lane row (full-rate VALU, no LDS pipe).
template <int CTRL>
__device__ __forceinline__ float dppmv(float x) {
    int i = __float_as_int(x);
    return __int_as_float(__builtin_amdgcn_update_dpp(i, i, CTRL, 0xF, 0xF, false));
}
__device__ __forceinline__ void red16_max(float* v) {
#pragma unroll
    for (int r = 0; r < 4; ++r) v[r] = fmaxf(v[r], dppmv<0xB1>(v[r]));
#pragma unroll
    for (int r = 0; r < 4; ++r) v[r] = fmaxf(v[r], dppmv<0x4E>(v[r]));
#pragma unroll
    for (int r = 0; r < 4; ++r) v[r] = fmaxf(v[r], dppmv<0x124>(v[r]));
#pragma unroll
    for (int r = 0; r < 4; ++r) v[r] = fmaxf(v[r], dppmv<0x128>(v[r]));
}
__device__ __forceinline__ void red16_sum(float* v) {
#pragma unroll
    for (int r = 0; r < 4; ++r) v[r] += dppmv<0xB1>(v[r]);
#pragma unroll
    for (int r = 0; r < 4; ++r) v[r] += dppmv<0x4E>(v[r]);
#pragma unroll
    for (int r = 0; r < 4; ++r) v[r] += dppmv<0x124>(v[r]);
#pragma unroll
    for (int r = 0; r < 4; ++r) v[r] += dppmv<0x128>(v[r]);
}

// ---------------- merged f32 -> bf16 converts (3 tensors, one dispatch) -----------
__global__ void k_convert3(const float* __restrict__ x, const float* __restrict__ wa,
                           const float* __restrict__ wp,
                           unsigned short* __restrict__ xb, unsigned short* __restrict__ wab,
                           unsigned short* __restrict__ wpb) {
    const int id = blockIdx.x;
    const float* src; unsigned short* dst; int base, n_src4;
    if (id < 8192)       { src = x;  dst = xb;  base = id;         n_src4 = 2097152; }
    else if (id < 14592) { src = wa; dst = wab; base = id - 8192;  n_src4 = 1581056; }
    else                 { src = wp; dst = wpb; base = id - 14592; n_src4 = 1048576; }
    int i = base * 256 + threadIdx.x;
    u16x4 o;
    if (i < n_src4) {
        v4f v = *(const v4f*)(src + (size_t)i * 4);
        o[0] = f2bf(v[0]); o[1] = f2bf(v[1]); o[2] = f2bf(v[2]); o[3] = f2bf(v[3]);
    } else {
        o[0] = 0; o[1] = 0; o[2] = 0; o[3] = 0;
    }
    *(u16x4*)(dst + (size_t)i * 4) = o;
}

// ---------------- BM_x256 8-phase NT GEMM (m201 template, plain HIP) --------------
template <int BM_, typename OutT>
__launch_bounds__(512, 2)
__global__ void k_gemm8(const unsigned short* __restrict__ A,
                        const unsigned short* __restrict__ Bm,
                        OutT* __restrict__ C,
                        int K, int lda, int ldb, int ldc, int nmax) {
    constexpr int MI  = BM_ / 32;     // M-frags per wave (8 or 4)
    constexpr int NPH = MI / 2;       // phases per K-tile (4 or 2)
    __shared__ unsigned short As[2][BM_ * 64];
    __shared__ unsigned short Bs[2][256 * 64];
    const int t = threadIdx.x;
    const int lane = t & 63;
    const int wid  = t >> 6;
    const int wr = wid >> 2, wc = wid & 3;       // wave grid 2M x 4N
    const int bm = blockIdx.x, bn = blockIdx.y;
    const int fro = lane & 15, fk = lane >> 4;

    const int srow  = lane >> 3;
    const size_t scol = (size_t)(((lane & 7) ^ srow) * 8);

    const unsigned short* Abase = A  + (size_t)(bm * BM_) * lda;
    const unsigned short* Bbase = Bm + (size_t)(bn * 256) * ldb;

    f32x4 acc[MI][4];
#pragma unroll
    for (int i = 0; i < MI; ++i)
#pragma unroll
        for (int j = 0; j < 4; ++j) acc[i][j] = (f32x4){0.f, 0.f, 0.f, 0.f};

#pragma unroll
    for (int h = 0; h < 2; ++h)
#pragma unroll
        for (int c8 = 0; c8 < 2; ++c8) {
            const int rr = h * 128 + wid * 16 + c8 * 8;
            if (BM_ == 256 || h == 0)
                gl_lds16(Abase + (size_t)(rr + srow) * lda + scol, &As[0][rr * 64]);
            gl_lds16(Bbase + (size_t)(rr + srow) * ldb + scol, &Bs[0][rr * 64]);
        }

    int cur = 0;
    for (int kt = 0; kt < K; kt += 64) {
        asm volatile("s_waitcnt vmcnt(0)" ::: "memory");
        __builtin_amdgcn_s_barrier();
        __builtin_amdgcn_sched_barrier(0);
        const bool pf = (kt + 64 < K);
        const int nxt = cur ^ 1;
        const int kn = kt + 64;

        short8 bf_[4][2];
#pragma unroll
        for (int q = 0; q < NPH; ++q) {
            short8 af[2][2];
#pragma unroll
            for (int im = 0; im < 2; ++im)
#pragma unroll
                for (int kk = 0; kk < 2; ++kk) {
                    const int ar = wr * (BM_ / 2) + (q * 2 + im) * 16 + fro;
                    af[im][kk] = *(const short8*)&As[cur][ar * 64 + ((kk * 4 + fk) ^ (ar & 7)) * 8];
                }
            if (q == 0) {
#pragma unroll
                for (int ni = 0; ni < 4; ++ni)
#pragma unroll
                    for (int kk = 0; kk < 2; ++kk) {
                        const int br = wc * 64 + ni * 16 + fro;
                        bf_[ni][kk] = *(const short8*)&Bs[cur][br * 64 + ((kk * 4 + fk) ^ (br & 7)) * 8];
                    }
            }
            if (pf) {
                if (BM_ == 256) {
                    const int h = q & 1;
#pragma unroll
                    for (int c8 = 0; c8 < 2; ++c8) {
                        const int rr = h * 128 + wid * 16 + c8 * 8;
                        if ((q >> 1) == 0)
                            gl_lds16(Abase + (size_t)(rr + srow) * lda + kn + scol, &As[nxt][rr * 64]);
                        else
                            gl_lds16(Bbase + (size_t)(rr + srow) * ldb + kn + scol, &Bs[nxt][rr * 64]);
                    }
                } else {
                    if (q == 0) {
#pragma unroll
                        for (int c8 = 0; c8 < 2; ++c8) {
                            const int rr = wid * 16 + c8 * 8;
                            gl_lds16(Abase + (size_t)(rr + srow) * lda + kn + scol, &As[nxt][rr * 64]);
                        }
                    } else {
#pragma unroll
                        for (int h = 0; h < 2; ++h)
#pragma unroll
                            for (int c8 = 0; c8 < 2; ++c8) {
                                const int rr = h * 128 + wid * 16 + c8 * 8;
                                gl_lds16(Bbase + (size_t)(rr + srow) * ldb + kn + scol, &Bs[nxt][rr * 64]);
                            }
                    }
                }
            }
            __builtin_amdgcn_s_setprio(1);
#pragma unroll
            for (int im = 0; im < 2; ++im)
#pragma unroll
                for (int ni = 0; ni < 4; ++ni)
#pragma unroll
                    for (int kk = 0; kk < 2; ++kk)
                        acc[q * 2 + im][ni] = __builtin_amdgcn_mfma_f32_16x16x32_bf16(
                            af[im][kk], bf_[ni][kk], acc[q * 2 + im][ni], 0, 0, 0);
            __builtin_amdgcn_s_setprio(0);
            __builtin_amdgcn_s_barrier();
        }
        cur ^= 1;
    }

    const int col16 = lane & 15, rbase = (lane >> 4) * 4;
    const int gr0 = bm * BM_ + wr * (BM_ / 2);
    const int gc0 = bn * 256 + wc * 64;
#pragma unroll
    for (int mi = 0; mi < MI; ++mi)
#pragma unroll
        for (int ni = 0; ni < 4; ++ni) {
            const int gcol = gc0 + ni * 16 + col16;
            if (gcol < nmax) {
#pragma unroll
                for (int r = 0; r < 4; ++r) {
                    const int grow = gr0 + mi * 16 + rbase + r;
                    float v = acc[mi][ni][r];
                    if constexpr (sizeof(OutT) == 2)
                        C[(size_t)grow * ldc + gcol] = (OutT)f2bf(v);
                    else
                        C[(size_t)grow * ldc + gcol] = (OutT)v;
                }
            }
        }
}

// ---------------- merged RMSNorm+RoPE (blocks <20480) + V-transpose (rest) --------
// q rows (hh<16) are pre-scaled by SCALE2_ so attn scores arrive in log2 domain.
__global__ void k_normtrans(unsigned short* __restrict__ qkv,
                            const float* __restrict__ cosT, const float* __restrict__ sinT,
                            const float* __restrict__ qw, const float* __restrict__ kw,
                            unsigned short* __restrict__ vt) {
    __shared__ unsigned short tile[64][65];
    const int id = blockIdx.x;
    if (id < 20480) {
        const int lane = threadIdx.x & 63;
        const int row  = id * 4 + (threadIdx.x >> 6);
        const int tok  = row / 20;
        const int hh   = row - tok * 20;
        const int tpos = tok & (T_ - 1);
        unsigned short* rp = qkv + (size_t)tok * NPAD + (hh < 16 ? hh * 128 : 2048 + (hh - 16) * 128);
        const float* w = (hh < 16) ? qw : kw;
        const float sc_ = (hh < 16) ? SCALE2_ : 1.0f;
        float e1 = bf2f(rp[lane]);
        float e2 = bf2f(rp[lane + 64]);
        float ss = e1 * e1 + e2 * e2;
#pragma unroll
        for (int m = 1; m < 64; m <<= 1) ss += __shfl_xor(ss, m);
        float inv = rsqrtf(ss * (1.0f / 128.0f) + 1e-5f);
        float n1 = e1 * inv * w[lane];
        float n2 = e2 * inv * w[lane + 64];
        float c = cosT[tpos * 64 + lane];
        float s = sinT[tpos * 64 + lane];
        rp[lane]      = f2bf((n1 * c - n2 * s) * sc_);
        rp[lane + 64] = f2bf((n2 * c + n1 * s) * sc_);
    } else {
        const int t2 = id - 20480;                 // 0..511
        const int b = (t2 & 7) >> 2, g = t2 & 3;
        const int s0 = ((t2 >> 3) & 31) * 64, d0 = (t2 >> 8) * 64;
        const int tx = threadIdx.x & 63, ty0 = threadIdx.x >> 6;
        const unsigned short* src = qkv + (size_t)(b * T_ + s0) * NPAD + 2560 + g * 128 + d0;
#pragma unroll
        for (int r = 0; r < 16; ++r) {
            int ty = ty0 * 16 + r;
            tile[ty][tx] = src[(size_t)ty * NPAD + tx];
        }
        __syncthreads();
        unsigned short* dstp = vt + ((size_t)(b * GG + g) * 128 + d0) * T_ + s0;
#pragma unroll
        for (int r = 0; r < 16; ++r) {
            int ty = ty0 * 16 + r;
            dstp[(size_t)ty * T_ + tx] = tile[tx][ty];
        }
    }
}

// ---------------- flash attention + gate ------------------------------------------
// r10 balanced pairing (waves 0-3 tile pr, waves 4-7 tile 31-pr, shared staging),
// SINGLE-buffered K/V (48KB LDS -> 3 blocks/CU; inter-block overlap covers the lost
// stage/compute overlap), T13 defer-rescale, pre-scaled q (no per-tile scale mul),
// diagonal-only mask branch, f2bf_fast P-store.
__launch_bounds__(512, 6)
__global__ void k_attn(const unsigned short* __restrict__ qkv,
                       const unsigned short* __restrict__ vt,
                       unsigned short* __restrict__ ao) {
    __shared__ unsigned short Ks[64 * 128];   // 16KB
    __shared__ unsigned short Vs[128 * 64];   // 16KB
    __shared__ unsigned short Ps[8][16 * 64]; // 16KB, XOR-swizzled slots
    const int t = threadIdx.x;
    const int lane = t & 63;
    const int wid  = t >> 6;              // 0..7
    const int id = blockIdx.x;
    const int bg = id & 7;                // -> XCD
    const int hh = (id >> 3) & 3;
    const int prx = (id >> 5) & 7;
    const int pr = (id & 256) ? (15 - prx) : prx;
    const int b = bg >> 2, g = bg & 3, h = g * 4 + hh;
    const int fro = lane & 15, fk = lane >> 4;
    const int rbase = fk * 4;

    const int qt  = (wid < 4) ? pr : 31 - pr;       // this wave's q-tile
    const int wq  = wid & 3;
    const int q0w = qt * 64 + wq * 16;
    const int nt_own  = qt + 1;
    const int nt_loop = 32 - pr;

    const unsigned short* kg0 = qkv + (size_t)(b * T_) * NPAD + 2048 + g * 128;
    const unsigned short* vg0 = vt + (size_t)(b * GG + g) * 128 * T_;

    // Q fragments (pre-scaled by SCALE2_ in normtrans)
    short8 qf[4];
    const unsigned short* qp = qkv + (size_t)(b * T_ + q0w + fro) * NPAD + h * 128 + fk * 8;
#pragma unroll
    for (int kb = 0; kb < 4; ++kb) qf[kb] = *(const short8*)(qp + kb * 32);

    float m_r[4], l_r[4];
    f32x4 o[8];
#pragma unroll
    for (int r = 0; r < 4; ++r) { m_r[r] = -1e30f; l_r[r] = 0.f; }
#pragma unroll
    for (int d = 0; d < 8; ++d) o[d] = (f32x4){0.f, 0.f, 0.f, 0.f};

    // staging: 16 K-chunks + 16 V-chunks over 8 waves -> 2 each
    const int cp0 = wid * 2;

    for (int ti = 0; ti < nt_loop; ++ti) {
        const int s0 = ti * 64;
        __syncthreads();                  // all waves done with previous tile
#pragma unroll
        for (int p = 0; p < 2; ++p) {
            const int cp = cp0 + p;
            const int kr = cp * 4 + (lane >> 4);
            const int sK = lane & 15;
            gl_lds16(kg0 + (size_t)(s0 + kr) * NPAD + (size_t)((sK ^ (kr & 7)) * 8), &Ks[cp * 512]);
            const int d  = cp * 8 + (lane >> 3);
            const int sV = lane & 7;
            gl_lds16(vg0 + (size_t)d * T_ + s0 + (size_t)((sV ^ (d & 7)) * 8), &Vs[cp * 512]);
        }
        __syncthreads();                  // compiler drains vmcnt(0) before barrier

        if (ti < nt_own) {
            // ---- QK^T: S[16 q][64 kv] (already log2-scaled via q) ----
            f32x4 sc[4];
#pragma unroll
            for (int jb = 0; jb < 4; ++jb) sc[jb] = (f32x4){0.f, 0.f, 0.f, 0.f};
#pragma unroll
            for (int jb = 0; jb < 4; ++jb) {
                const int kr = jb * 16 + fro;
#pragma unroll
                for (int kb = 0; kb < 4; ++kb) {
                    short8 kf = *(const short8*)&Ks[kr * 128 + 8 * ((kb * 4 + fk) ^ (kr & 7))];
                    sc[jb] = __builtin_amdgcn_mfma_f32_16x16x32_bf16(qf[kb], kf, sc[jb], 0, 0, 0);
                }
            }
            // ---- causal mask: diagonal tile only (wave-uniform branch) ----
            if (ti == qt) {
#pragma unroll
                for (int jb = 0; jb < 4; ++jb)
#pragma unroll
                    for (int r = 0; r < 4; ++r)
                        if ((jb * 16 + fro) > (wq * 16 + rbase + r)) sc[jb][r] = -1e30f;
            }
            // ---- online softmax (DPP reductions, T13 defer-rescale) ----
            float mx[4], rs[4];
#pragma unroll
            for (int r = 0; r < 4; ++r)
                mx[r] = fmaxf(fmaxf(sc[0][r], sc[1][r]), fmaxf(sc[2][r], sc[3][r]));
            red16_max(mx);
            bool grow = false;
#pragma unroll
            for (int r = 0; r < 4; ++r) grow = grow || (mx[r] > m_r[r] + 8.f);
            if (__any(grow ? 1 : 0)) {
#pragma unroll
                for (int r = 0; r < 4; ++r) {
                    float mn = fmaxf(m_r[r], mx[r]);
                    float fs = exp2f(m_r[r] - mn);
                    m_r[r] = mn;
                    l_r[r] *= fs;
#pragma unroll
                    for (int d = 0; d < 8; ++d) o[d][r] *= fs;
                }
            }
#pragma unroll
            for (int jb = 0; jb < 4; ++jb)
#pragma unroll
                for (int r = 0; r < 4; ++r) sc[jb][r] = exp2f(sc[jb][r] - m_r[r]);
#pragma unroll
            for (int r = 0; r < 4; ++r)
                rs[r] = (sc[0][r] + sc[1][r]) + (sc[2][r] + sc[3][r]);
            red16_sum(rs);
#pragma unroll
            for (int r = 0; r < 4; ++r) l_r[r] += rs[r];
            // ---- P -> LDS (transpose to A-layout, XOR-swizzled 16B slots) ----
            unsigned short* pw = &Ps[wid][0];
#pragma unroll
            for (int jb = 0; jb < 4; ++jb)
#pragma unroll
                for (int r = 0; r < 4; ++r) {
                    const int row = rbase + r;
                    const int slot = jb * 2 + (fro >> 3);
                    pw[row * 64 + ((slot ^ (row & 7)) * 8 + (fro & 7))] = f2bf_fast(sc[jb][r]);
                }
            asm volatile("s_waitcnt lgkmcnt(0)" ::: "memory");
            __builtin_amdgcn_sched_barrier(0);
            short8 pa[2];
#pragma unroll
            for (int ks = 0; ks < 2; ++ks)
                pa[ks] = *(const short8*)&Ps[wid][fro * 64 + ((ks * 4 + fk) ^ (fro & 7)) * 8];
            // ---- PV ----
#pragma unroll
            for (int ks = 0; ks < 2; ++ks)
#pragma unroll
                for (int db = 0; db < 8; ++db) {
                    const int d = db * 16 + fro;
                    short8 vf = *(const short8*)&Vs[d * 64 + 8 * ((ks * 4 + fk) ^ (d & 7))];
                    o[db] = __builtin_amdgcn_mfma_f32_16x16x32_bf16(pa[ks], vf, o[db], 0, 0, 0);
                }
        }
    }
    // ---- epilogue: 1/l, sigmoid gate, store bf16 ----
#pragma unroll
    for (int r = 0; r < 4; ++r) {
        const int qrow = q0w + rbase + r;
        float gv = bf2f(qkv[(size_t)(b * T_ + qrow) * NPAD + QKVD + h]);
        float sg = 1.f / (1.f + __expf(-gv));
        float invl = sg / l_r[r];
        unsigned short* orow = ao + (size_t)(b * T_ + qrow) * 2048 + h * 128;
#pragma unroll
        for (int db = 0; db < 8; ++db)
            orow[db * 16 + fro] = f2bf(o[db][r] * invl);
    }
}

extern "C" void kernel_launch(void* const* d_in, const int* in_sizes, int n_in,
                              void* d_out, int out_size, void* d_ws, size_t ws_size,
                              hipStream_t stream) {
    const float* x      = (const float*)d_in[0];
    const float* cosT   = (const float*)d_in[1];
    const float* sinT   = (const float*)d_in[2];
    const float* W_attn = (const float*)d_in[3];
    const float* qw     = (const float*)d_in[4];
    const float* kw     = (const float*)d_in[5];
    const float* W_proj = (const float*)d_in[6];

    char* ws = (char*)d_ws;
    const size_t OFF_XB   = 0;                       // 4096*2048*2   = 16777216
    const size_t OFF_WAB  = 16777216;                // 3200*2048*2   = 13107200
    const size_t OFF_WPB  = 29884416;                // 2048*2048*2   =  8388608
    const size_t OFF_QKV  = 38273024;                // 4096*3200*2   = 26214400
    const size_t OFF_VT   = 64487424;                // 2*4*128*2048*2=  4194304
    const size_t OFF_AO   = 68681728;                // 4096*2048*2   = 16777216
    const size_t NEED     = 85458944;
    if (ws_size < NEED) return;

    unsigned short* xb   = (unsigned short*)(ws + OFF_XB);
    unsigned short* wab  = (unsigned short*)(ws + OFF_WAB);
    unsigned short* wpb  = (unsigned short*)(ws + OFF_WPB);
    unsigned short* qkvb = (unsigned short*)(ws + OFF_QKV);
    unsigned short* vtb  = (unsigned short*)(ws + OFF_VT);
    unsigned short* aob  = (unsigned short*)(ws + OFF_AO);

    k_convert3<<<18688, 256, 0, stream>>>(x, W_attn, W_proj, xb, wab, wpb);
    k_gemm8<256, unsigned short><<<dim3(16, 13), 512, 0, stream>>>(xb, wab, qkvb, 2048, 2048, 2048, NPAD, NPAD);
    k_normtrans<<<20992, 256, 0, stream>>>(qkvb, cosT, sinT, qw, kw, vtb);
    k_attn<<<512, 512, 0, stream>>>(qkvb, vtb, aob);
    k_gemm8<128, float><<<dim3(32, 8), 512, 0, stream>>>(aob, wpb, (float*)d_out, 2048, 2048, 2048, 2048, 2048);
}

// Round 17
// 211.034 us; speedup vs baseline: 1.7729x; 1.7729x over previous
//
#include <hip/hip_runtime.h>

#define T_   2048
#define BB   2
#define CC   2048
#define HH   16
#define GG   4
#define HSS  128
#define QKVD 3072          // (H+2G)*HS
#define NQKV 3088          // + H gate cols
#define NPAD 3200          // padded to 25*128
#define SCALE_ 0.08838834764831845f   // 1/sqrt(128)
#define SCALE2_ (0.08838834764831845f * 1.4426950408889634f)   // 1/sqrt(128) * log2(e)

typedef __attribute__((ext_vector_type(8))) short  short8;
typedef __attribute__((ext_vector_type(4))) float  f32x4;
typedef __attribute__((ext_vector_type(4))) int    v4i;
typedef __attribute__((ext_vector_type(4))) float  v4f;
typedef __attribute__((ext_vector_type(4))) unsigned short u16x4;

typedef const void __attribute__((address_space(1)))* gas1_t;
typedef void __attribute__((address_space(3)))* as3_t;

__device__ __forceinline__ void gl_lds16(const void* g, void* l) {
    __builtin_amdgcn_global_load_lds((gas1_t)g, (as3_t)l, 16, 0, 0);
}

__device__ __forceinline__ unsigned short f2bf(float f) {
    unsigned u = __float_as_uint(f);
    u += 0x7fffu + ((u >> 16) & 1u);   // RNE
    return (unsigned short)(u >> 16);
}
// round-half-up: P values are positive exp2 outputs, bias negligible, 2 ops not 4
__device__ __forceinline__ unsigned short f2bf_fast(float f) {
    return (unsigned short)((__float_as_uint(f) + 0x8000u) >> 16);
}
__device__ __forceinline__ float bf2f(unsigned short h) {
    return __uint_as_float(((unsigned)h) << 16);
}

// DPP cross-lane move within a 16-lane row (full-rate VALU, no LDS pipe).
template <int CTRL>
__device__ __forceinline__ float dppmv(float x) {
    int i = __float_as_int(x);
    return __int_as_float(__builtin_amdgcn_update_dpp(i, i, CTRL, 0xF, 0xF, false));
}
__device__ __forceinline__ void red16_max(float* v) {
#pragma unroll
    for (int r = 0; r < 4; ++r) v[r] = fmaxf(v[r], dppmv<0xB1>(v[r]));
#pragma unroll
    for (int r = 0; r < 4; ++r) v[r] = fmaxf(v[r], dppmv<0x4E>(v[r]));
#pragma unroll
    for (int r = 0; r < 4; ++r) v[r] = fmaxf(v[r], dppmv<0x124>(v[r]));
#pragma unroll
    for (int r = 0; r < 4; ++r) v[r] = fmaxf(v[r], dppmv<0x128>(v[r]));
}
__device__ __forceinline__ void red16_sum(float* v) {
#pragma unroll
    for (int r = 0; r < 4; ++r) v[r] += dppmv<0xB1>(v[r]);
#pragma unroll
    for (int r = 0; r < 4; ++r) v[r] += dppmv<0x4E>(v[r]);
#pragma unroll
    for (int r = 0; r < 4; ++r) v[r] += dppmv<0x124>(v[r]);
#pragma unroll
    for (int r = 0; r < 4; ++r) v[r] += dppmv<0x128>(v[r]);
}

// ---------------- merged f32 -> bf16 converts (3 tensors, one dispatch) -----------
__global__ void k_convert3(const float* __restrict__ x, const float* __restrict__ wa,
                           const float* __restrict__ wp,
                           unsigned short* __restrict__ xb, unsigned short* __restrict__ wab,
                           unsigned short* __restrict__ wpb) {
    const int id = blockIdx.x;
    const float* src; unsigned short* dst; int base, n_src4;
    if (id < 8192)       { src = x;  dst = xb;  base = id;         n_src4 = 2097152; }
    else if (id < 14592) { src = wa; dst = wab; base = id - 8192;  n_src4 = 1581056; }
    else                 { src = wp; dst = wpb; base = id - 14592; n_src4 = 1048576; }
    int i = base * 256 + threadIdx.x;
    u16x4 o;
    if (i < n_src4) {
        v4f v = *(const v4f*)(src + (size_t)i * 4);
        o[0] = f2bf(v[0]); o[1] = f2bf(v[1]); o[2] = f2bf(v[2]); o[3] = f2bf(v[3]);
    } else {
        o[0] = 0; o[1] = 0; o[2] = 0; o[3] = 0;
    }
    *(u16x4*)(dst + (size_t)i * 4) = o;
}

// ---------------- BM_x256 8-phase NT GEMM (m201 template, plain HIP) --------------
template <int BM_, typename OutT>
__launch_bounds__(512, 2)
__global__ void k_gemm8(const unsigned short* __restrict__ A,
                        const unsigned short* __restrict__ Bm,
                        OutT* __restrict__ C,
                        int K, int lda, int ldb, int ldc, int nmax) {
    constexpr int MI  = BM_ / 32;     // M-frags per wave (8 or 4)
    constexpr int NPH = MI / 2;       // phases per K-tile (4 or 2)
    __shared__ unsigned short As[2][BM_ * 64];
    __shared__ unsigned short Bs[2][256 * 64];
    const int t = threadIdx.x;
    const int lane = t & 63;
    const int wid  = t >> 6;
    const int wr = wid >> 2, wc = wid & 3;       // wave grid 2M x 4N
    const int bm = blockIdx.x, bn = blockIdx.y;
    const int fro = lane & 15, fk = lane >> 4;

    const int srow  = lane >> 3;
    const size_t scol = (size_t)(((lane & 7) ^ srow) * 8);

    const unsigned short* Abase = A  + (size_t)(bm * BM_) * lda;
    const unsigned short* Bbase = Bm + (size_t)(bn * 256) * ldb;

    f32x4 acc[MI][4];
#pragma unroll
    for (int i = 0; i < MI; ++i)
#pragma unroll
        for (int j = 0; j < 4; ++j) acc[i][j] = (f32x4){0.f, 0.f, 0.f, 0.f};

#pragma unroll
    for (int h = 0; h < 2; ++h)
#pragma unroll
        for (int c8 = 0; c8 < 2; ++c8) {
            const int rr = h * 128 + wid * 16 + c8 * 8;
            if (BM_ == 256 || h == 0)
                gl_lds16(Abase + (size_t)(rr + srow) * lda + scol, &As[0][rr * 64]);
            gl_lds16(Bbase + (size_t)(rr + srow) * ldb + scol, &Bs[0][rr * 64]);
        }

    int cur = 0;
    for (int kt = 0; kt < K; kt += 64) {
        asm volatile("s_waitcnt vmcnt(0)" ::: "memory");
        __builtin_amdgcn_s_barrier();
        __builtin_amdgcn_sched_barrier(0);
        const bool pf = (kt + 64 < K);
        const int nxt = cur ^ 1;
        const int kn = kt + 64;

        short8 bf_[4][2];
#pragma unroll
        for (int q = 0; q < NPH; ++q) {
            short8 af[2][2];
#pragma unroll
            for (int im = 0; im < 2; ++im)
#pragma unroll
                for (int kk = 0; kk < 2; ++kk) {
                    const int ar = wr * (BM_ / 2) + (q * 2 + im) * 16 + fro;
                    af[im][kk] = *(const short8*)&As[cur][ar * 64 + ((kk * 4 + fk) ^ (ar & 7)) * 8];
                }
            if (q == 0) {
#pragma unroll
                for (int ni = 0; ni < 4; ++ni)
#pragma unroll
                    for (int kk = 0; kk < 2; ++kk) {
                        const int br = wc * 64 + ni * 16 + fro;
                        bf_[ni][kk] = *(const short8*)&Bs[cur][br * 64 + ((kk * 4 + fk) ^ (br & 7)) * 8];
                    }
            }
            if (pf) {
                if (BM_ == 256) {
                    const int h = q & 1;
#pragma unroll
                    for (int c8 = 0; c8 < 2; ++c8) {
                        const int rr = h * 128 + wid * 16 + c8 * 8;
                        if ((q >> 1) == 0)
                            gl_lds16(Abase + (size_t)(rr + srow) * lda + kn + scol, &As[nxt][rr * 64]);
                        else
                            gl_lds16(Bbase + (size_t)(rr + srow) * ldb + kn + scol, &Bs[nxt][rr * 64]);
                    }
                } else {
                    if (q == 0) {
#pragma unroll
                        for (int c8 = 0; c8 < 2; ++c8) {
                            const int rr = wid * 16 + c8 * 8;
                            gl_lds16(Abase + (size_t)(rr + srow) * lda + kn + scol, &As[nxt][rr * 64]);
                        }
                    } else {
#pragma unroll
                        for (int h = 0; h < 2; ++h)
#pragma unroll
                            for (int c8 = 0; c8 < 2; ++c8) {
                                const int rr = h * 128 + wid * 16 + c8 * 8;
                                gl_lds16(Bbase + (size_t)(rr + srow) * ldb + kn + scol, &Bs[nxt][rr * 64]);
                            }
                    }
                }
            }
            __builtin_amdgcn_s_setprio(1);
#pragma unroll
            for (int im = 0; im < 2; ++im)
#pragma unroll
                for (int ni = 0; ni < 4; ++ni)
#pragma unroll
                    for (int kk = 0; kk < 2; ++kk)
                        acc[q * 2 + im][ni] = __builtin_amdgcn_mfma_f32_16x16x32_bf16(
                            af[im][kk], bf_[ni][kk], acc[q * 2 + im][ni], 0, 0, 0);
            __builtin_amdgcn_s_setprio(0);
            __builtin_amdgcn_s_barrier();
        }
        cur ^= 1;
    }

    const int col16 = lane & 15, rbase = (lane >> 4) * 4;
    const int gr0 = bm * BM_ + wr * (BM_ / 2);
    const int gc0 = bn * 256 + wc * 64;
#pragma unroll
    for (int mi = 0; mi < MI; ++mi)
#pragma unroll
        for (int ni = 0; ni < 4; ++ni) {
            const int gcol = gc0 + ni * 16 + col16;
            if (gcol < nmax) {
#pragma unroll
                for (int r = 0; r < 4; ++r) {
                    const int grow = gr0 + mi * 16 + rbase + r;
                    float v = acc[mi][ni][r];
                    if constexpr (sizeof(OutT) == 2)
                        C[(size_t)grow * ldc + gcol] = (OutT)f2bf(v);
                    else
                        C[(size_t)grow * ldc + gcol] = (OutT)v;
                }
            }
        }
}

// ---------------- merged RMSNorm+RoPE (blocks <20480) + V-transpose (rest) --------
// q rows (hh<16) are pre-scaled by SCALE2_ so attn scores arrive in log2 domain.
__global__ void k_normtrans(unsigned short* __restrict__ qkv,
                            const float* __restrict__ cosT, const float* __restrict__ sinT,
                            const float* __restrict__ qw, const float* __restrict__ kw,
                            unsigned short* __restrict__ vt) {
    __shared__ unsigned short tile[64][65];
    const int id = blockIdx.x;
    if (id < 20480) {
        const int lane = threadIdx.x & 63;
        const int row  = id * 4 + (threadIdx.x >> 6);
        const int tok  = row / 20;
        const int hh   = row - tok * 20;
        const int tpos = tok & (T_ - 1);
        unsigned short* rp = qkv + (size_t)tok * NPAD + (hh < 16 ? hh * 128 : 2048 + (hh - 16) * 128);
        const float* w = (hh < 16) ? qw : kw;
        const float sc_ = (hh < 16) ? SCALE2_ : 1.0f;
        float e1 = bf2f(rp[lane]);
        float e2 = bf2f(rp[lane + 64]);
        float ss = e1 * e1 + e2 * e2;
#pragma unroll
        for (int m = 1; m < 64; m <<= 1) ss += __shfl_xor(ss, m);
        float inv = rsqrtf(ss * (1.0f / 128.0f) + 1e-5f);
        float n1 = e1 * inv * w[lane];
        float n2 = e2 * inv * w[lane + 64];
        float c = cosT[tpos * 64 + lane];
        float s = sinT[tpos * 64 + lane];
        rp[lane]      = f2bf((n1 * c - n2 * s) * sc_);
        rp[lane + 64] = f2bf((n2 * c + n1 * s) * sc_);
    } else {
        const int t2 = id - 20480;                 // 0..511
        const int b = (t2 & 7) >> 2, g = t2 & 3;
        const int s0 = ((t2 >> 3) & 31) * 64, d0 = (t2 >> 8) * 64;
        const int tx = threadIdx.x & 63, ty0 = threadIdx.x >> 6;
        const unsigned short* src = qkv + (size_t)(b * T_ + s0) * NPAD + 2560 + g * 128 + d0;
#pragma unroll
        for (int r = 0; r < 16; ++r) {
            int ty = ty0 * 16 + r;
            tile[ty][tx] = src[(size_t)ty * NPAD + tx];
        }
        __syncthreads();
        unsigned short* dstp = vt + ((size_t)(b * GG + g) * 128 + d0) * T_ + s0;
#pragma unroll
        for (int r = 0; r < 16; ++r) {
            int ty = ty0 * 16 + r;
            dstp[(size_t)ty * T_ + tx] = tile[tx][ty];
        }
    }
}

// ---------------- flash attention + gate ------------------------------------------
// r10 balanced pairing + single-buffered K/V (48KB LDS -> 3 blocks/CU via LDS limit;
// launch_bounds min-waves kept at 4/EU so regalloc is NOT constrained — the r16
// (512,6) spilled to scratch: VGPR 40, FETCH 291MB). T13 defer-rescale, pre-scaled q,
// diagonal-only mask, f2bf_fast P-store.
__launch_bounds__(512, 4)
__global__ void k_attn(const unsigned short* __restrict__ qkv,
                       const unsigned short* __restrict__ vt,
                       unsigned short* __restrict__ ao) {
    __shared__ unsigned short Ks[64 * 128];   // 16KB
    __shared__ unsigned short Vs[128 * 64];   // 16KB
    __shared__ unsigned short Ps[8][16 * 64]; // 16KB, XOR-swizzled slots
    const int t = threadIdx.x;
    const int lane = t & 63;
    const int wid  = t >> 6;              // 0..7
    const int id = blockIdx.x;
    const int bg = id & 7;                // -> XCD
    const int hh = (id >> 3) & 3;
    const int prx = (id >> 5) & 7;
    const int pr = (id & 256) ? (15 - prx) : prx;
    const int b = bg >> 2, g = bg & 3, h = g * 4 + hh;
    const int fro = lane & 15, fk = lane >> 4;
    const int rbase = fk * 4;

    const int qt  = (wid < 4) ? pr : 31 - pr;       // this wave's q-tile
    const int wq  = wid & 3;
    const int q0w = qt * 64 + wq * 16;
    const int nt_own  = qt + 1;
    const int nt_loop = 32 - pr;

    const unsigned short* kg0 = qkv + (size_t)(b * T_) * NPAD + 2048 + g * 128;
    const unsigned short* vg0 = vt + (size_t)(b * GG + g) * 128 * T_;

    // Q fragments (pre-scaled by SCALE2_ in normtrans)
    short8 qf[4];
    const unsigned short* qp = qkv + (size_t)(b * T_ + q0w + fro) * NPAD + h * 128 + fk * 8;
#pragma unroll
    for (int kb = 0; kb < 4; ++kb) qf[kb] = *(const short8*)(qp + kb * 32);

    float m_r[4], l_r[4];
    f32x4 o[8];
#pragma unroll
    for (int r = 0; r < 4; ++r) { m_r[r] = -1e30f; l_r[r] = 0.f; }
#pragma unroll
    for (int d = 0; d < 8; ++d) o[d] = (f32x4){0.f, 0.f, 0.f, 0.f};

    // staging: 16 K-chunks + 16 V-chunks over 8 waves -> 2 each
    const int cp0 = wid * 2;

    for (int ti = 0; ti < nt_loop; ++ti) {
        const int s0 = ti * 64;
        __syncthreads();                  // all waves done with previous tile
#pragma unroll
        for (int p = 0; p < 2; ++p) {
            const int cp = cp0 + p;
            const int kr = cp * 4 + (lane >> 4);
            const int sK = lane & 15;
            gl_lds16(kg0 + (size_t)(s0 + kr) * NPAD + (size_t)((sK ^ (kr & 7)) * 8), &Ks[cp * 512]);
            const int d  = cp * 8 + (lane >> 3);
            const int sV = lane & 7;
            gl_lds16(vg0 + (size_t)d * T_ + s0 + (size_t)((sV ^ (d & 7)) * 8), &Vs[cp * 512]);
        }
        __syncthreads();                  // compiler drains vmcnt(0) before barrier

        if (ti < nt_own) {
            // ---- QK^T: S[16 q][64 kv] (already log2-scaled via q) ----
            f32x4 sc[4];
#pragma unroll
            for (int jb = 0; jb < 4; ++jb) sc[jb] = (f32x4){0.f, 0.f, 0.f, 0.f};
#pragma unroll
            for (int jb = 0; jb < 4; ++jb) {
                const int kr = jb * 16 + fro;
#pragma unroll
                for (int kb = 0; kb < 4; ++kb) {
                    short8 kf = *(const short8*)&Ks[kr * 128 + 8 * ((kb * 4 + fk) ^ (kr & 7))];
                    sc[jb] = __builtin_amdgcn_mfma_f32_16x16x32_bf16(qf[kb], kf, sc[jb], 0, 0, 0);
                }
            }
            // ---- causal mask: diagonal tile only (wave-uniform branch) ----
            if (ti == qt) {
#pragma unroll
                for (int jb = 0; jb < 4; ++jb)
#pragma unroll
                    for (int r = 0; r < 4; ++r)
                        if ((jb * 16 + fro) > (wq * 16 + rbase + r)) sc[jb][r] = -1e30f;
            }
            // ---- online softmax (DPP reductions, T13 defer-rescale) ----
            float mx[4], rs[4];
#pragma unroll
            for (int r = 0; r < 4; ++r)
                mx[r] = fmaxf(fmaxf(sc[0][r], sc[1][r]), fmaxf(sc[2][r], sc[3][r]));
            red16_max(mx);
            bool grow = false;
#pragma unroll
            for (int r = 0; r < 4; ++r) grow = grow || (mx[r] > m_r[r] + 8.f);
            if (__any(grow ? 1 : 0)) {
#pragma unroll
                for (int r = 0; r < 4; ++r) {
                    float mn = fmaxf(m_r[r], mx[r]);
                    float fs = exp2f(m_r[r] - mn);
                    m_r[r] = mn;
                    l_r[r] *= fs;
#pragma unroll
                    for (int d = 0; d < 8; ++d) o[d][r] *= fs;
                }
            }
#pragma unroll
            for (int jb = 0; jb < 4; ++jb)
#pragma unroll
                for (int r = 0; r < 4; ++r) sc[jb][r] = exp2f(sc[jb][r] - m_r[r]);
#pragma unroll
            for (int r = 0; r < 4; ++r)
                rs[r] = (sc[0][r] + sc[1][r]) + (sc[2][r] + sc[3][r]);
            red16_sum(rs);
#pragma unroll
            for (int r = 0; r < 4; ++r) l_r[r] += rs[r];
            // ---- P -> LDS (transpose to A-layout, XOR-swizzled 16B slots) ----
            unsigned short* pw = &Ps[wid][0];
#pragma unroll
            for (int jb = 0; jb < 4; ++jb)
#pragma unroll
                for (int r = 0; r < 4; ++r) {
                    const int row = rbase + r;
                    const int slot = jb * 2 + (fro >> 3);
                    pw[row * 64 + ((slot ^ (row & 7)) * 8 + (fro & 7))] = f2bf_fast(sc[jb][r]);
                }
            asm volatile("s_waitcnt lgkmcnt(0)" ::: "memory");
            __builtin_amdgcn_sched_barrier(0);
            short8 pa[2];
#pragma unroll
            for (int ks = 0; ks < 2; ++ks)
                pa[ks] = *(const short8*)&Ps[wid][fro * 64 + ((ks * 4 + fk) ^ (fro & 7)) * 8];
            // ---- PV ----
#pragma unroll
            for (int ks = 0; ks < 2; ++ks)
#pragma unroll
                for (int db = 0; db < 8; ++db) {
                    const int d = db * 16 + fro;
                    short8 vf = *(const short8*)&Vs[d * 64 + 8 * ((ks * 4 + fk) ^ (d & 7))];
                    o[db] = __builtin_amdgcn_mfma_f32_16x16x32_bf16(pa[ks], vf, o[db], 0, 0, 0);
                }
        }
    }
    // ---- epilogue: 1/l, sigmoid gate, store bf16 ----
#pragma unroll
    for (int r = 0; r < 4; ++r) {
        const int qrow = q0w + rbase + r;
        float gv = bf2f(qkv[(size_t)(b * T_ + qrow) * NPAD + QKVD + h]);
        float sg = 1.f / (1.f + __expf(-gv));
        float invl = sg / l_r[r];
        unsigned short* orow = ao + (size_t)(b * T_ + qrow) * 2048 + h * 128;
#pragma unroll
        for (int db = 0; db < 8; ++db)
            orow[db * 16 + fro] = f2bf(o[db][r] * invl);
    }
}

extern "C" void kernel_launch(void* const* d_in, const int* in_sizes, int n_in,
                              void* d_out, int out_size, void* d_ws, size_t ws_size,
                              hipStream_t stream) {
    const float* x      = (const float*)d_in[0];
    const float* cosT   = (const float*)d_in[1];
    const float* sinT   = (const float*)d_in[2];
    const float* W_attn = (const float*)d_in[3];
    const float* qw     = (const float*)d_in[4];
    const float* kw     = (const float*)d_in[5];
    const float* W_proj = (const float*)d_in[6];

    char* ws = (char*)d_ws;
    const size_t OFF_XB   = 0;                       // 4096*2048*2   = 16777216
    const size_t OFF_WAB  = 16777216;                // 3200*2048*2   = 13107200
    const size_t OFF_WPB  = 29884416;                // 2048*2048*2   =  8388608
    const size_t OFF_QKV  = 38273024;                // 4096*3200*2   = 26214400
    const size_t OFF_VT   = 64487424;                // 2*4*128*2048*2=  4194304
    const size_t OFF_AO   = 68681728;                // 4096*2048*2   = 16777216
    const size_t NEED     = 85458944;
    if (ws_size < NEED) return;

    unsigned short* xb   = (unsigned short*)(ws + OFF_XB);
    unsigned short* wab  = (unsigned short*)(ws + OFF_WAB);
    unsigned short* wpb  = (unsigned short*)(ws + OFF_WPB);
    unsigned short* qkvb = (unsigned short*)(ws + OFF_QKV);
    unsigned short* vtb  = (unsigned short*)(ws + OFF_VT);
    unsigned short* aob  = (unsigned short*)(ws + OFF_AO);

    k_convert3<<<18688, 256, 0, stream>>>(x, W_attn, W_proj, xb, wab, wpb);
    k_gemm8<256, unsigned short><<<dim3(16, 13), 512, 0, stream>>>(xb, wab, qkvb, 2048, 2048, 2048, NPAD, NPAD);
    k_normtrans<<<20992, 256, 0, stream>>>(qkvb, cosT, sinT, qw, kw, vtb);
    k_attn<<<512, 512, 0, stream>>>(qkvb, vtb, aob);
    k_gemm8<128, float><<<dim3(32, 8), 512, 0, stream>>>(aob, wpb, (float*)d_out, 2048, 2048, 2048, 2048, 2048);
}